// Round 21
// baseline (294.211 us; speedup 1.0000x reference)
//
#include <hip/hip_runtime.h>
#include <stdint.h>
#include <math.h>

#define BT   65536
#define H    4
#define K    512
#define DH   256
#define EPSN 1e-12f
#define EPSL 1e-10f
#define TAU  0.03f
#define CTH  0.970446f      // exp(-TAU), multiplicative e-domain threshold
#define CMAX 16
#define NREP 8              // avg_probs accumulator replicas
#define LOG2E 1.4426950408889634f

typedef short bf16x8 __attribute__((ext_vector_type(8)));
typedef float f32x4  __attribute__((ext_vector_type(4)));

__device__ inline unsigned short f2bf(float f) {
  uint32_t u = __builtin_bit_cast(uint32_t, f);
  u += 0x7fffu + ((u >> 16) & 1u);
  return (unsigned short)(u >> 16);
}

// RNE pack of two f32 -> packed 2xbf16 in one v_cvt_pk_bf16_f32.
__device__ inline uint32_t pack_bf2(float lo, float hi) {
  uint32_t r;
  asm("v_cvt_pk_bf16_f32 %0, %1, %2" : "=v"(r) : "v"(lo), "v"(hi));
  return r;
}

// ---------------------------------------------------------------------------
// ws layout (float slots):
//   en_f  : [H][K][DH] fp32 normalized      524288
//   en_t  : tiled bf16, scaled by sc*log2e  131072 slots
//           layout: [h][kblk=k>>4][ks=d>>5][lane=(kg<<4)|arow][8]
//   avgp  : [NREP][H*K]                     16384
//   idx_ws: [BT][H] int                     262144
// ---------------------------------------------------------------------------

__global__ __launch_bounds__(256) void vq_prep(const float* __restrict__ emb,
                                               const float* __restrict__ scales,
                                               float* __restrict__ en_f,
                                               unsigned short* __restrict__ en_t,
                                               float* __restrict__ avgp) {
  const int hk = blockIdx.x;        // h*K + k
  const int t  = threadIdx.x;       // d
  const float v = emb[(size_t)hk * DH + t];
  float s = v * v;
#pragma unroll
  for (int m = 1; m < 64; m <<= 1) s += __shfl_xor(s, m);
  __shared__ float wsum[4];
  if ((t & 63) == 0) wsum[t >> 6] = s;
  __syncthreads();
  const float tot = wsum[0] + wsum[1] + wsum[2] + wsum[3];
  const float n   = fmaxf(sqrtf(tot), EPSN);
  const float vn  = v / n;
  en_f[(size_t)hk * DH + t] = vn;

  const int h    = hk >> 9, k = hk & (K - 1);
  const float s2 = scales[h] * LOG2E;            // exp(sc*x) == exp2(sc*log2e*x)
  const int kblk = k >> 4, arow = k & 15;
  const int ks   = t >> 5, kg = (t >> 3) & 3, e = t & 7;
  const int lane = (kg << 4) | arow;
  en_t[(((size_t)(h * 32 + kblk) * 8 + ks) * 64 + lane) * 8 + e] = f2bf(vn * s2);
  if (t < NREP) avgp[t * (H * K) + hk] = 0.0f;
}

// Block: 64 b-rows x 512 codes for one h. 512 threads = 8 waves.
// Wave w owns codes [64w, 64w+64): acc[4][4]; code = 64w+16mi+4kg+q,
// zrow = 16ni + arow. 64 acc AGPR + ~64 VGPR = 128 unified -> 4 waves/SIMD.
// r17 optimum (225us) + r21: per-thread redundant cross-wave combine
// (32 broadcast LDS reads) replaces the barrier + idle-lane t<64 phase.
// Barriers: 3 (stage | wredm ready | avg_lds ready).
__global__ __launch_bounds__(512, 4) void vq_main(
    const float* __restrict__ z_e, const float* __restrict__ emb,
    const float* __restrict__ en_f, const unsigned short* __restrict__ en_t,
    float* __restrict__ avgp, int* __restrict__ idx_ws,
    float* __restrict__ outq) {
  const int h     = blockIdx.y;
  const int bbase = blockIdx.x * 64;
  const int t     = threadIdx.x;
  const int w     = t >> 6;
  const int l     = t & 63;
  const int arow  = l & 15;
  const int kg    = l >> 4;                      // 0..3

  __shared__ unsigned short a_lds[64 * 256];     // 32 KiB RAW z bf16, swizzled
  __shared__ float norms[64];
  __shared__ float invn_l[64];
  __shared__ float wredm[8][64];                 // per-wave max
  __shared__ float wreds[8][64];                 // per-wave exp-sum
  __shared__ __align__(16) unsigned short cand[64][CMAX];
  __shared__ int   cnt[64];
  __shared__ float avg_lds[512];                 // per-block avg_probs partial

  // ---- stage: load z row (8 lanes/row), pack RAW -> LDS immediately;
  //      ss-reduce proceeds in parallel (not on the LDS-write path) ----
  {
    const int row = t >> 3;                      // 0..63
    const int c8  = t & 7;
    const float* zp = z_e + (size_t)(bbase + row) * (H * DH) + h * DH;
    float4 q[8];
    float ss = 0.0f;
    const int swz = (row & 7) << 4;
#pragma unroll
    for (int j = 0; j < 8; j++) {
      q[j] = *(const float4*)(zp + c8 * 4 + j * 32);
      const int d = c8 * 4 + j * 32;
      uint2 pk;
      pk.x = pack_bf2(q[j].x, q[j].y);
      pk.y = pack_bf2(q[j].z, q[j].w);
      *(uint2*)((char*)a_lds + row * 512 + ((d * 2) ^ swz)) = pk;
      ss += q[j].x * q[j].x + q[j].y * q[j].y + q[j].z * q[j].z + q[j].w * q[j].w;
    }
    ss += __shfl_xor(ss, 1);
    ss += __shfl_xor(ss, 2);
    ss += __shfl_xor(ss, 4);
    const float n = fmaxf(sqrtf(ss), EPSN);
    if (c8 == 0) { norms[row] = n; invn_l[row] = 1.0f / n; }
    if (t < 64) cnt[t] = 0;
  }

  // ---- prefetch ks=0 A-fragments (independent of LDS/barrier) ----
  const unsigned short* ep =
      en_t + (((size_t)(h * 32 + w * 4) * 8) * 64 + l) * 8;
  bf16x8 ef0[4];
#pragma unroll
  for (int mi = 0; mi < 4; mi++)
    ef0[mi] = *(const bf16x8*)(ep + (size_t)(mi * 8) * 512);

  __syncthreads();                               // b1

  // ---- MFMA GEMM: A = en_t tiles (coalesced 1KiB), B = raw z rows (LDS) ----
  f32x4 acc[4][4];
#pragma unroll
  for (int mi = 0; mi < 4; mi++)
#pragma unroll
    for (int ni = 0; ni < 4; ni++) acc[mi][ni] = (f32x4){0.f, 0.f, 0.f, 0.f};

#pragma unroll
  for (int ks = 0; ks < 8; ks++) {
    bf16x8 ef[4];
    if (ks == 0) {
#pragma unroll
      for (int mi = 0; mi < 4; mi++) ef[mi] = ef0[mi];
    } else {
#pragma unroll
      for (int mi = 0; mi < 4; mi++)
        ef[mi] = *(const bf16x8*)(ep + (size_t)(mi * 8 + ks) * 512);
    }
    bf16x8 zf[4];
#pragma unroll
    for (int ni = 0; ni < 4; ni++) {
      const int rr = ni * 16 + arow;
      const int kb = (ks * 64) | (kg * 16);
      zf[ni] = *(const bf16x8*)((const char*)a_lds + rr * 512 +
                                (kb ^ ((rr & 7) << 4)));
    }
#pragma unroll
    for (int mi = 0; mi < 4; mi++)
#pragma unroll
      for (int ni = 0; ni < 4; ni++)
        acc[mi][ni] = __builtin_amdgcn_mfma_f32_16x16x32_bf16(ef[mi], zf[ni],
                                                              acc[mi][ni], 0, 0, 0);
  }

  // ---- pass 1: e = exp2(acc * invn[row]); per-lane {max, sum} ----
  float rn[4];
#pragma unroll
  for (int ni = 0; ni < 4; ni++) rn[ni] = invn_l[ni * 16 + arow];
  float m1[4], es[4];
#pragma unroll
  for (int ni = 0; ni < 4; ni++) { m1[ni] = 0.0f; es[ni] = 0.0f; }
#pragma unroll
  for (int mi = 0; mi < 4; mi++)
#pragma unroll
    for (int ni = 0; ni < 4; ni++)
#pragma unroll
      for (int q = 0; q < 4; q++) {
        const float e = __builtin_amdgcn_exp2f(acc[mi][ni][q] * rn[ni]);
        acc[mi][ni][q] = e;
        m1[ni] = fmaxf(m1[ni], e);
        es[ni] += e;
      }
  // combine over kg (masks 16, 32)
#pragma unroll
  for (int m = 16; m < 64; m <<= 1) {
#pragma unroll
    for (int ni = 0; ni < 4; ni++) {
      m1[ni] = fmaxf(m1[ni], __shfl_xor(m1[ni], m));
      es[ni] += __shfl_xor(es[ni], m);
    }
  }
  if (kg == 0) {
#pragma unroll
    for (int ni = 0; ni < 4; ni++) {
      const int r = ni * 16 + arow;
      wredm[w][r] = m1[ni];
      wreds[w][r] = es[ni];
    }
  }
  __syncthreads();                               // b2: wredm/wreds ready

  // ---- per-thread redundant cross-wave combine (broadcast LDS reads) ----
  float rs[4], th[4];
#pragma unroll
  for (int ni = 0; ni < 4; ni++) {
    const int r = ni * 16 + arow;
    float a1 = wredm[0][r], s = wreds[0][r];
#pragma unroll
    for (int ww = 1; ww < 8; ww++) {
      a1 = fmaxf(a1, wredm[ww][r]);
      s += wreds[ww][r];
    }
    th[ni] = a1 * CTH;
    rs[ni] = __builtin_amdgcn_rcpf(s);           // softmax denom; loose tolerance
  }

  // ---- pass 2: avg_probs partials -> LDS + candidate scan (e >= thr) ----
#pragma unroll
  for (int mi = 0; mi < 4; mi++)
#pragma unroll
    for (int q = 0; q < 4; q++) {
      float vs = 0.0f;
#pragma unroll
      for (int ni = 0; ni < 4; ni++) {
        const float e = acc[mi][ni][q];
        vs = fmaf(e, rs[ni], vs);
        if (e >= th[ni]) {
          const int r = ni * 16 + arow;
          const int p = atomicAdd(&cnt[r], 1);
          if (p < CMAX)
            cand[r][p] = (unsigned short)(w * 64 + mi * 16 + kg * 4 + q);
        }
      }
      vs += __shfl_xor(vs, 1);
      vs += __shfl_xor(vs, 2);
      vs += __shfl_xor(vs, 4);
      vs += __shfl_xor(vs, 8);
      if (arow == 0) avg_lds[w * 64 + mi * 16 + kg * 4 + q] = vs;
    }
  __syncthreads();                               // b3: avg_lds + cand final

  // ---- one fire-and-forget global atomic per thread for avg_probs ----
  {
    float* ap = avgp + (blockIdx.x & (NREP - 1)) * (H * K) + h * K;
    atomicAdd(&ap[t], avg_lds[t]);
  }

  // ---- refine + idx write + gather, fully wave-local ----
  int best8[8];
#pragma unroll
  for (int i = 0; i < 8; i++) {
    const int r = w * 8 + i;
    int c = cnt[r];
    int best;
    if (c <= 1) {
      best = cand[r][0];                 // cnt>=1 always: max itself passes thr
    } else {
      if (c > CMAX) c = CMAX;
      const float nrm = norms[r];
      const float4 zq = *(const float4*)(z_e + (size_t)(bbase + r) * (H * DH) +
                                         h * DH + l * 4);
      const float zn0 = zq.x / nrm, zn1 = zq.y / nrm,
                  zn2 = zq.z / nrm, zn3 = zq.w / nrm;
      float bv = -INFINITY; int bi = 1 << 30;
      for (int j = 0; j < c; j++) {
        const int cd = cand[r][j];
        const float4 eq = *(const float4*)(en_f + ((size_t)(h * K) + cd) * DH + l * 4);
        float d0 = fmaf(zn0, eq.x, fmaf(zn1, eq.y, fmaf(zn2, eq.z, zn3 * eq.w)));
#pragma unroll
        for (int m = 1; m < 64; m <<= 1) d0 += __shfl_xor(d0, m);
        if (d0 > bv || (d0 == bv && cd < bi)) { bv = d0; bi = cd; }
      }
      best = bi;                         // lane-uniform
    }
    best8[i] = best;
    if (l == i) idx_ws[(size_t)(bbase + r) * H + h] = best;
  }

  // ---- batched z_q gather: 8 rows/wave, all loads in flight ----
  {
    float4 gv[8];
#pragma unroll
    for (int i = 0; i < 8; i++)
      gv[i] = *(const float4*)(emb + ((size_t)(h * K) + best8[i]) * DH + l * 4);
#pragma unroll
    for (int i = 0; i < 8; i++)
      *(float4*)(outq + (size_t)(bbase + w * 8 + i) * (H * DH) + h * DH + l * 4) =
          gv[i];
  }
}

// Fused tail: blocks 0..255 compute combined (int32 wraparound, as float);
// block 256 computes perplexity.
__global__ __launch_bounds__(256) void vq_tail(const int* __restrict__ idx_ws,
                                               const float* __restrict__ avgp,
                                               float* __restrict__ out_comb,
                                               float* __restrict__ out_perp) {
  const int t = threadIdx.x;
  if (blockIdx.x < 256) {
    const int b = blockIdx.x * 256 + t;
    const int* p = idx_ws + (size_t)b * H;
    uint32_t cv = (uint32_t)p[0];
    cv = cv * 512u + (uint32_t)p[1];
    cv = cv * 512u + (uint32_t)p[2];
    cv = cv * 512u + (uint32_t)p[3];
    out_comb[b] = (float)(int32_t)cv;
    return;
  }
  float sh[H] = {0.f, 0.f, 0.f, 0.f};
  for (int i = t; i < H * K; i += 256) {
    const int h = i >> 9;
    float a = 0.0f;
#pragma unroll
    for (int c = 0; c < NREP; c++) a += avgp[c * (H * K) + i];
    a /= 65536.0f;
    sh[h] += a * logf(a + EPSL);
  }
  __shared__ float red[4][H];
#pragma unroll
  for (int h = 0; h < H; h++) {
    float s = sh[h];
#pragma unroll
    for (int m = 1; m < 64; m <<= 1) s += __shfl_xor(s, m);
    if ((t & 63) == 0) red[t >> 6][h] = s;
  }
  __syncthreads();
  if (t == 0) {
    float p = 0.0f;
#pragma unroll
    for (int h = 0; h < H; h++) {
      const float s = red[0][h] + red[1][h] + red[2][h] + red[3][h];
      p += expf(-s);
    }
    out_perp[0] = p * 0.25f;
  }
}

extern "C" void kernel_launch(void* const* d_in, const int* in_sizes, int n_in,
                              void* d_out, int out_size, void* d_ws, size_t ws_size,
                              hipStream_t stream) {
  const float* z_e    = (const float*)d_in[0];
  const float* emb    = (const float*)d_in[1];
  const float* scales = (const float*)d_in[2];
  float* out = (float*)d_out;

  float*          en_f   = (float*)d_ws;                        // 524288
  unsigned short* en_t   = (unsigned short*)(en_f + (size_t)H * K * DH);
  float*          avgp   = (float*)(en_t + (size_t)H * K * DH); // NREP*2048
  int*            idx_ws = (int*)(avgp + NREP * H * K);         // 262144

  hipLaunchKernelGGL(vq_prep, dim3(H * K), dim3(256), 0, stream,
                     emb, scales, en_f, en_t, avgp);
  hipLaunchKernelGGL(vq_main, dim3(BT / 64, H), dim3(512), 0, stream,
                     z_e, emb, en_f, en_t, avgp, idx_ws, out);
  hipLaunchKernelGGL(vq_tail, dim3(BT / 256 + 1), dim3(256), 0, stream,
                     idx_ws, avgp, out + (size_t)BT * H * DH,
                     out + (size_t)BT * H * DH + BT);
}

// Round 22
// 224.945 us; speedup vs baseline: 1.3079x; 1.3079x over previous
//
#include <hip/hip_runtime.h>
#include <stdint.h>
#include <math.h>

#define BT   65536
#define H    4
#define K    512
#define DH   256
#define EPSN 1e-12f
#define EPSL 1e-10f
#define TAU  0.03f
#define CTH  0.970446f      // exp(-TAU), multiplicative e-domain threshold
#define CMAX 16
#define NREP 8              // avg_probs accumulator replicas
#define LOG2E 1.4426950408889634f

typedef short bf16x8 __attribute__((ext_vector_type(8)));
typedef float f32x4  __attribute__((ext_vector_type(4)));

__device__ inline unsigned short f2bf(float f) {
  uint32_t u = __builtin_bit_cast(uint32_t, f);
  u += 0x7fffu + ((u >> 16) & 1u);
  return (unsigned short)(u >> 16);
}

// RNE pack of two f32 -> packed 2xbf16 in one v_cvt_pk_bf16_f32.
__device__ inline uint32_t pack_bf2(float lo, float hi) {
  uint32_t r;
  asm("v_cvt_pk_bf16_f32 %0, %1, %2" : "=v"(r) : "v"(lo), "v"(hi));
  return r;
}

// ---------------------------------------------------------------------------
// ws layout (float slots):
//   en_f  : [H][K][DH] fp32 normalized      524288
//   en_t  : tiled bf16, scaled by sc*log2e  131072 slots
//           layout: [h][kblk=k>>4][ks=d>>5][lane=(kg<<4)|arow][8]
//   avgp  : [NREP][H*K]                     16384
//   idx_ws: [BT][H] int                     262144
// ---------------------------------------------------------------------------

__global__ __launch_bounds__(256) void vq_prep(const float* __restrict__ emb,
                                               const float* __restrict__ scales,
                                               float* __restrict__ en_f,
                                               unsigned short* __restrict__ en_t,
                                               float* __restrict__ avgp) {
  const int hk = blockIdx.x;        // h*K + k
  const int t  = threadIdx.x;       // d
  const float v = emb[(size_t)hk * DH + t];
  float s = v * v;
#pragma unroll
  for (int m = 1; m < 64; m <<= 1) s += __shfl_xor(s, m);
  __shared__ float wsum[4];
  if ((t & 63) == 0) wsum[t >> 6] = s;
  __syncthreads();
  const float tot = wsum[0] + wsum[1] + wsum[2] + wsum[3];
  const float n   = fmaxf(sqrtf(tot), EPSN);
  const float vn  = v / n;
  en_f[(size_t)hk * DH + t] = vn;

  const int h    = hk >> 9, k = hk & (K - 1);
  const float s2 = scales[h] * LOG2E;            // exp(sc*x) == exp2(sc*log2e*x)
  const int kblk = k >> 4, arow = k & 15;
  const int ks   = t >> 5, kg = (t >> 3) & 3, e = t & 7;
  const int lane = (kg << 4) | arow;
  en_t[(((size_t)(h * 32 + kblk) * 8 + ks) * 64 + lane) * 8 + e] = f2bf(vn * s2);
  if (t < NREP) avgp[t * (H * K) + hk] = 0.0f;
}

// Block: 64 b-rows x 512 codes for one h. 512 threads = 8 waves.
// Wave w owns codes [64w, 64w+64): acc[4][4]; code = 64w+16mi+4kg+q,
// zrow = 16ni + arow. 64 acc AGPR + ~64 VGPR = 128 unified -> 4 waves/SIMD.
// Measured optimum over 21 variants (225-226 us, reproduced 2x):
//  - RAW z staged (norm OFF the stage critical path; the r17 +35us win)
//  - row norm folded in as e = exp2(acc * invn[row]); en_t pre-scaled sc*log2e
//  - en_t pre-tiled to fragment order -> 1KiB coalesced A-loads
//  - ks=0 A-fragments prefetched before the barrier
//  - shuffle+array cross-wave reduce (LDS atomics r19 and redundant
//    per-thread combine r21 both regressed)
//  - argmax from TAU-candidate set; cnt>1 -> exact fp32 refine (bit-exact)
__global__ __launch_bounds__(512, 4) void vq_main(
    const float* __restrict__ z_e, const float* __restrict__ emb,
    const float* __restrict__ en_f, const unsigned short* __restrict__ en_t,
    float* __restrict__ avgp, int* __restrict__ idx_ws,
    float* __restrict__ outq) {
  const int h     = blockIdx.y;
  const int bbase = blockIdx.x * 64;
  const int t     = threadIdx.x;
  const int w     = t >> 6;
  const int l     = t & 63;
  const int arow  = l & 15;
  const int kg    = l >> 4;                      // 0..3

  __shared__ unsigned short a_lds[64 * 256];     // 32 KiB RAW z bf16, swizzled
  __shared__ float norms[64];
  __shared__ float invn_l[64];
  __shared__ float wredm[8][64];                 // per-wave max
  __shared__ float wreds[8][64];                 // per-wave exp-sum
  __shared__ __align__(16) unsigned short cand[64][CMAX];
  __shared__ float thr[64];                      // gmx * CTH
  __shared__ float Srec[64];                     // 1/sum
  __shared__ int   cnt[64];
  __shared__ float avg_lds[512];                 // per-block avg_probs partial

  // ---- stage: load z row (8 lanes/row), pack RAW -> LDS immediately;
  //      ss-reduce proceeds in parallel (not on the LDS-write path) ----
  {
    const int row = t >> 3;                      // 0..63
    const int c8  = t & 7;
    const float* zp = z_e + (size_t)(bbase + row) * (H * DH) + h * DH;
    float4 q[8];
    float ss = 0.0f;
    const int swz = (row & 7) << 4;
#pragma unroll
    for (int j = 0; j < 8; j++) {
      q[j] = *(const float4*)(zp + c8 * 4 + j * 32);
      const int d = c8 * 4 + j * 32;
      uint2 pk;
      pk.x = pack_bf2(q[j].x, q[j].y);
      pk.y = pack_bf2(q[j].z, q[j].w);
      *(uint2*)((char*)a_lds + row * 512 + ((d * 2) ^ swz)) = pk;
      ss += q[j].x * q[j].x + q[j].y * q[j].y + q[j].z * q[j].z + q[j].w * q[j].w;
    }
    ss += __shfl_xor(ss, 1);
    ss += __shfl_xor(ss, 2);
    ss += __shfl_xor(ss, 4);
    const float n = fmaxf(sqrtf(ss), EPSN);
    if (c8 == 0) { norms[row] = n; invn_l[row] = 1.0f / n; }
    if (t < 64) cnt[t] = 0;
  }

  // ---- prefetch ks=0 A-fragments (independent of LDS/barrier) ----
  const unsigned short* ep =
      en_t + (((size_t)(h * 32 + w * 4) * 8) * 64 + l) * 8;
  bf16x8 ef0[4];
#pragma unroll
  for (int mi = 0; mi < 4; mi++)
    ef0[mi] = *(const bf16x8*)(ep + (size_t)(mi * 8) * 512);

  __syncthreads();

  // ---- MFMA GEMM: A = en_t tiles (coalesced 1KiB), B = raw z rows (LDS) ----
  f32x4 acc[4][4];
#pragma unroll
  for (int mi = 0; mi < 4; mi++)
#pragma unroll
    for (int ni = 0; ni < 4; ni++) acc[mi][ni] = (f32x4){0.f, 0.f, 0.f, 0.f};

#pragma unroll
  for (int ks = 0; ks < 8; ks++) {
    bf16x8 ef[4];
    if (ks == 0) {
#pragma unroll
      for (int mi = 0; mi < 4; mi++) ef[mi] = ef0[mi];
    } else {
#pragma unroll
      for (int mi = 0; mi < 4; mi++)
        ef[mi] = *(const bf16x8*)(ep + (size_t)(mi * 8 + ks) * 512);
    }
    bf16x8 zf[4];
#pragma unroll
    for (int ni = 0; ni < 4; ni++) {
      const int rr = ni * 16 + arow;
      const int kb = (ks * 64) | (kg * 16);
      zf[ni] = *(const bf16x8*)((const char*)a_lds + rr * 512 +
                                (kb ^ ((rr & 7) << 4)));
    }
#pragma unroll
    for (int mi = 0; mi < 4; mi++)
#pragma unroll
      for (int ni = 0; ni < 4; ni++)
        acc[mi][ni] = __builtin_amdgcn_mfma_f32_16x16x32_bf16(ef[mi], zf[ni],
                                                              acc[mi][ni], 0, 0, 0);
  }

  // ---- pass 1: e = exp2(acc * invn[row]); per-lane {max, sum} ----
  float rn[4];
#pragma unroll
  for (int ni = 0; ni < 4; ni++) rn[ni] = invn_l[ni * 16 + arow];
  float m1[4], es[4];
#pragma unroll
  for (int ni = 0; ni < 4; ni++) { m1[ni] = 0.0f; es[ni] = 0.0f; }
#pragma unroll
  for (int mi = 0; mi < 4; mi++)
#pragma unroll
    for (int ni = 0; ni < 4; ni++)
#pragma unroll
      for (int q = 0; q < 4; q++) {
        const float e = __builtin_amdgcn_exp2f(acc[mi][ni][q] * rn[ni]);
        acc[mi][ni][q] = e;
        m1[ni] = fmaxf(m1[ni], e);
        es[ni] += e;
      }
  // combine over kg (masks 16, 32)
#pragma unroll
  for (int m = 16; m < 64; m <<= 1) {
#pragma unroll
    for (int ni = 0; ni < 4; ni++) {
      m1[ni] = fmaxf(m1[ni], __shfl_xor(m1[ni], m));
      es[ni] += __shfl_xor(es[ni], m);
    }
  }
  if (kg == 0) {
#pragma unroll
    for (int ni = 0; ni < 4; ni++) {
      const int r = ni * 16 + arow;
      wredm[w][r] = m1[ni];
      wreds[w][r] = es[ni];
    }
  }
  __syncthreads();
  if (t < 64) {
    float a1 = 0.0f, s = 0.0f;
#pragma unroll
    for (int ww = 0; ww < 8; ww++) {
      a1 = fmaxf(a1, wredm[ww][t]);
      s += wreds[ww][t];
    }
    thr[t] = a1 * CTH; Srec[t] = 1.0f / s;
  }
  __syncthreads();

  // ---- pass 2: avg_probs partials -> LDS + candidate scan (e >= thr) ----
  {
    float rs[4], th[4];
#pragma unroll
    for (int ni = 0; ni < 4; ni++) {
      const int r = ni * 16 + arow;
      rs[ni] = Srec[r];
      th[ni] = thr[r];
    }
#pragma unroll
    for (int mi = 0; mi < 4; mi++)
#pragma unroll
      for (int q = 0; q < 4; q++) {
        float vs = 0.0f;
#pragma unroll
        for (int ni = 0; ni < 4; ni++) {
          const float e = acc[mi][ni][q];
          vs = fmaf(e, rs[ni], vs);
          if (e >= th[ni]) {
            const int r = ni * 16 + arow;
            const int p = atomicAdd(&cnt[r], 1);
            if (p < CMAX)
              cand[r][p] = (unsigned short)(w * 64 + mi * 16 + kg * 4 + q);
          }
        }
        vs += __shfl_xor(vs, 1);
        vs += __shfl_xor(vs, 2);
        vs += __shfl_xor(vs, 4);
        vs += __shfl_xor(vs, 8);
        if (arow == 0) avg_lds[w * 64 + mi * 16 + kg * 4 + q] = vs;
      }
  }
  __syncthreads();

  // ---- one fire-and-forget global atomic per thread for avg_probs ----
  {
    float* ap = avgp + (blockIdx.x & (NREP - 1)) * (H * K) + h * K;
    atomicAdd(&ap[t], avg_lds[t]);
  }

  // ---- refine + idx write + gather, fully wave-local ----
  int best8[8];
#pragma unroll
  for (int i = 0; i < 8; i++) {
    const int r = w * 8 + i;
    int c = cnt[r];
    int best;
    if (c <= 1) {
      best = cand[r][0];                 // cnt>=1 always: max itself passes thr
    } else {
      if (c > CMAX) c = CMAX;
      const float nrm = norms[r];
      const float4 zq = *(const float4*)(z_e + (size_t)(bbase + r) * (H * DH) +
                                         h * DH + l * 4);
      const float zn0 = zq.x / nrm, zn1 = zq.y / nrm,
                  zn2 = zq.z / nrm, zn3 = zq.w / nrm;
      float bv = -INFINITY; int bi = 1 << 30;
      for (int j = 0; j < c; j++) {
        const int cd = cand[r][j];
        const float4 eq = *(const float4*)(en_f + ((size_t)(h * K) + cd) * DH + l * 4);
        float d0 = fmaf(zn0, eq.x, fmaf(zn1, eq.y, fmaf(zn2, eq.z, zn3 * eq.w)));
#pragma unroll
        for (int m = 1; m < 64; m <<= 1) d0 += __shfl_xor(d0, m);
        if (d0 > bv || (d0 == bv && cd < bi)) { bv = d0; bi = cd; }
      }
      best = bi;                         // lane-uniform
    }
    best8[i] = best;
    if (l == i) idx_ws[(size_t)(bbase + r) * H + h] = best;
  }

  // ---- batched z_q gather: 8 rows/wave, all loads in flight ----
  {
    float4 gv[8];
#pragma unroll
    for (int i = 0; i < 8; i++)
      gv[i] = *(const float4*)(emb + ((size_t)(h * K) + best8[i]) * DH + l * 4);
#pragma unroll
    for (int i = 0; i < 8; i++)
      *(float4*)(outq + (size_t)(bbase + w * 8 + i) * (H * DH) + h * DH + l * 4) =
          gv[i];
  }
}

// Fused tail: blocks 0..255 compute combined (int32 wraparound, as float);
// block 256 computes perplexity.
__global__ __launch_bounds__(256) void vq_tail(const int* __restrict__ idx_ws,
                                               const float* __restrict__ avgp,
                                               float* __restrict__ out_comb,
                                               float* __restrict__ out_perp) {
  const int t = threadIdx.x;
  if (blockIdx.x < 256) {
    const int b = blockIdx.x * 256 + t;
    const int* p = idx_ws + (size_t)b * H;
    uint32_t cv = (uint32_t)p[0];
    cv = cv * 512u + (uint32_t)p[1];
    cv = cv * 512u + (uint32_t)p[2];
    cv = cv * 512u + (uint32_t)p[3];
    out_comb[b] = (float)(int32_t)cv;
    return;
  }
  float sh[H] = {0.f, 0.f, 0.f, 0.f};
  for (int i = t; i < H * K; i += 256) {
    const int h = i >> 9;
    float a = 0.0f;
#pragma unroll
    for (int c = 0; c < NREP; c++) a += avgp[c * (H * K) + i];
    a /= 65536.0f;
    sh[h] += a * logf(a + EPSL);
  }
  __shared__ float red[4][H];
#pragma unroll
  for (int h = 0; h < H; h++) {
    float s = sh[h];
#pragma unroll
    for (int m = 1; m < 64; m <<= 1) s += __shfl_xor(s, m);
    if ((t & 63) == 0) red[t >> 6][h] = s;
  }
  __syncthreads();
  if (t == 0) {
    float p = 0.0f;
#pragma unroll
    for (int h = 0; h < H; h++) {
      const float s = red[0][h] + red[1][h] + red[2][h] + red[3][h];
      p += expf(-s);
    }
    out_perp[0] = p * 0.25f;
  }
}

extern "C" void kernel_launch(void* const* d_in, const int* in_sizes, int n_in,
                              void* d_out, int out_size, void* d_ws, size_t ws_size,
                              hipStream_t stream) {
  const float* z_e    = (const float*)d_in[0];
  const float* emb    = (const float*)d_in[1];
  const float* scales = (const float*)d_in[2];
  float* out = (float*)d_out;

  float*          en_f   = (float*)d_ws;                        // 524288
  unsigned short* en_t   = (unsigned short*)(en_f + (size_t)H * K * DH);
  float*          avgp   = (float*)(en_t + (size_t)H * K * DH); // NREP*2048
  int*            idx_ws = (int*)(avgp + NREP * H * K);         // 262144

  hipLaunchKernelGGL(vq_prep, dim3(H * K), dim3(256), 0, stream,
                     emb, scales, en_f, en_t, avgp);
  hipLaunchKernelGGL(vq_main, dim3(BT / 64, H), dim3(512), 0, stream,
                     z_e, emb, en_f, en_t, avgp, idx_ws, out);
  hipLaunchKernelGGL(vq_tail, dim3(BT / 256 + 1), dim3(256), 0, stream,
                     idx_ws, avgp, out + (size_t)BT * H * DH,
                     out + (size_t)BT * H * DH + BT);
}